// Round 7
// baseline (101.538 us; speedup 1.0000x reference)
//
#include <hip/hip_runtime.h>
#include <hip/hip_bf16.h>

#define NB 2
#define NS 2048
#define NH 16
#define ND 128
#define SROW (NH*ND)   // floats between consecutive s in [B,S,H,D] (= 2048)

#define QBLK 128       // q rows per block (4 waves x 32 q)
#define KBLK 64
#define NTHR 256
#define NT   (NS/KBLK) // 32 tiles

#define KSTR 136   // shorts; row bytes 272 (odd multiple of 16B)
#define VSTR 72    // shorts; row bytes 144

typedef __attribute__((ext_vector_type(4))) float f32x4;
typedef __attribute__((ext_vector_type(8))) __bf16 bf16x8;
typedef __attribute__((ext_vector_type(4))) __bf16 bf16x4;
typedef __attribute__((ext_vector_type(8))) short s16x8;
typedef __attribute__((ext_vector_type(4))) short s16x4;

__device__ __forceinline__ short f2bf(float f) {
  union { float f; unsigned u; } v; v.f = f;
  unsigned r = v.u + 0x7fffu + ((v.u >> 16) & 1u);
  return (short)(r >> 16);
}

// ---------------- pre-pass: K -> bf16 [B,H,S,D], scale*log2e folded ----------------
__global__ __launch_bounds__(256)
void prep_k(const float* __restrict__ K, short* __restrict__ Kb) {
  const float sc = 0.08838834764831845f * 1.4426950408889634f;
  size_t i = (size_t)blockIdx.x * 256 + threadIdx.x;   // one float4 per thread
  int g = (int)(i & 31);
  size_t row = i >> 5;                 // (b*S+s)*H + h
  int h = (int)(row & (NH - 1));
  size_t bs = row >> 4;                // b*S+s
  int s = (int)(bs & (NS - 1));
  int b = (int)(bs >> 11);
  float4 x = *(const float4*)(K + row * ND + g * 4);
  bf16x4 w = { (__bf16)(x.x * sc), (__bf16)(x.y * sc), (__bf16)(x.z * sc), (__bf16)(x.w * sc) };
  *(bf16x4*)(Kb + ((size_t)(b * NH + h) * NS + s) * ND + g * 4) = w;
}

// ---------------- pre-pass: V -> bf16 transposed [B,H,D,S] ----------------
__global__ __launch_bounds__(256)
void prep_v(const float* __restrict__ V, short* __restrict__ VT) {
  __shared__ short tile[64 * 72];
  int gid = blockIdx.x;
  int st = gid & 31;
  int dt = (gid >> 5) & 1;
  int bh = gid >> 6;
  int b = bh >> 4, h = bh & 15;
  int s0 = st * 64, d0 = dt * 64;
  const float* src = V + ((size_t)b * NS * NH + h) * ND;
#pragma unroll
  for (int it = 0; it < 4; ++it) {
    int idx = threadIdx.x + it * 256;
    int r = idx >> 4;
    int c = (idx & 15) * 4;
    float4 x = *(const float4*)(src + (size_t)(s0 + r) * SROW + d0 + c);
    bf16x4 w = { (__bf16)x.x, (__bf16)x.y, (__bf16)x.z, (__bf16)x.w };
    *(bf16x4*)&tile[r * 72 + c] = w;
  }
  __syncthreads();
  short* dst = VT + (size_t)bh * ND * NS;
#pragma unroll
  for (int it = 0; it < 2; ++it) {
    int idx = threadIdx.x + it * 256;
    int dr = idx >> 3;
    int c8 = (idx & 7) * 8;
    s16x8 w;
#pragma unroll
    for (int j = 0; j < 8; ++j) w[j] = tile[(c8 + j) * 72 + dr];
    *(s16x8*)(dst + (size_t)(d0 + dr) * NS + s0 + c8) = w;
  }
}

// -- main attention: XCD-swizzled, peeled + unroll-2 pipeline, deferred PV --
__global__ __launch_bounds__(NTHR, 2)
void attn_fwd7(const float* __restrict__ Q, const short* __restrict__ Kb,
               const short* __restrict__ VTb, float* __restrict__ O)
{
  __shared__ __align__(16) short kbuf[2][KBLK * KSTR];  // 2 x 17408 B
  __shared__ __align__(16) short vbuf[2][ND * VSTR];    // 2 x 18432 B

  const int tid  = threadIdx.x;
  const int wave = tid >> 6;
  const int lane = tid & 63;
  const int g    = lane >> 4;
  const int lr   = lane & 15;

  // XCD-aware swizzle: blocks resident on one XCD (L%8) cover only 4 bh values,
  // so each XCD's KV working set is 8 MB instead of 64 MB -> L2-local staging.
  const int L  = blockIdx.x;
  const int bh = (L & 7) + 8 * ((L >> 3) & 3);   // 0..31
  const int qb = L >> 5;                         // 0..15
  const int b  = bh >> 4;
  const int h  = bh & 15;

  const float* Qb = Q + ((size_t)b * NS * NH + h) * ND;
  float*       Ob = O + ((size_t)b * NS * NH + h) * ND;
  const short* Kbh = Kb  + (size_t)bh * NS * ND;
  const short* Vbh = VTb + (size_t)bh * ND * NS;

  const int wq0 = qb * QBLK + wave * 32;   // this wave's first q row (owns 32)

  // ---- Q fragments for both q-subtiles (B-operand layout), bf16 ----
  bf16x8 qf[2][4];
#pragma unroll
  for (int qt = 0; qt < 2; ++qt) {
    const float* qp = Qb + (size_t)(wq0 + qt * 16 + lr) * SROW;
#pragma unroll
    for (int kc = 0; kc < 4; ++kc) {
      const int d0 = kc * 32 + g * 8;
      float4 a = *(const float4*)(qp + d0);
      float4 c = *(const float4*)(qp + d0 + 4);
      bf16x8 f;
      f[0] = (__bf16)a.x; f[1] = (__bf16)a.y; f[2] = (__bf16)a.z; f[3] = (__bf16)a.w;
      f[4] = (__bf16)c.x; f[5] = (__bf16)c.y; f[6] = (__bf16)c.z; f[7] = (__bf16)c.w;
      qf[qt][kc] = f;
    }
  }

  f32x4 oacc[2][8];
#pragma unroll
  for (int qt = 0; qt < 2; ++qt)
#pragma unroll
    for (int dc = 0; dc < 8; ++dc) oacc[qt][dc] = (f32x4){0.f, 0.f, 0.f, 0.f};
  float lpart[2] = {0.f, 0.f};   // per-lane partial row sums (q = qt*16+lr)
  bf16x8 pf[2][2];               // P frags of PREVIOUS tile (deferred PV)

  // ---- per-thread staging coordinates (kt-invariant) ----
  const int vc = tid & 7;
  const int ksb = vc >> 2, q4 = vc & 3;
  const int vcol0 = ksb * 32 + ((q4 * 2) & 3) * 8 + (q4 >> 1) * 4;
  const int klo = (tid >> 4) * KSTR + (tid & 15) * 8;
  const int vlo = (tid >> 3) * VSTR + vcol0;

  const short* kp = Kbh + (tid >> 4) * ND + (tid & 15) * 8;
  const short* vp = Vbh + (size_t)(tid >> 3) * NS + vc * 8;

  s16x8 kreg[4], vreg[4];

#define LOAD_NEXT                                                              \
  {                                                                            \
    _Pragma("unroll")                                                          \
    for (int it = 0; it < 4; ++it) {                                           \
      kreg[it] = *(const s16x8*)(kp + it * (16 * ND));                         \
      vreg[it] = *(const s16x8*)(vp + (size_t)it * (32 * NS));                 \
    }                                                                          \
    kp += KBLK * ND;                                                           \
    vp += KBLK;                                                                \
  }

#define WRITE_LDS(KL, VL)                                                      \
  {                                                                            \
    _Pragma("unroll")                                                          \
    for (int it = 0; it < 4; ++it) {                                           \
      *(s16x8*)&(KL)[klo + it * (16 * KSTR)] = kreg[it];                       \
      s16x8 v = vreg[it];                                                      \
      s16x4 vlo4 = __builtin_shufflevector(v, v, 0, 1, 2, 3);                  \
      s16x4 vhi4 = __builtin_shufflevector(v, v, 4, 5, 6, 7);                  \
      *(s16x4*)&(VL)[vlo + it * (32 * VSTR)]     = vlo4;                       \
      *(s16x4*)&(VL)[vlo + it * (32 * VSTR) + 8] = vhi4;                       \
    }                                                                          \
  }

#define QK_SOFTMAX(KL)                                                         \
  {                                                                            \
    f32x4 sacc[2][4];                                                          \
    __builtin_amdgcn_s_setprio(1);                                             \
    _Pragma("unroll")                                                          \
    for (int nb = 0; nb < 4; ++nb) {                                           \
      f32x4 a0 = {0.f, 0.f, 0.f, 0.f};                                         \
      f32x4 a1 = {0.f, 0.f, 0.f, 0.f};                                         \
      _Pragma("unroll")                                                        \
      for (int kc = 0; kc < 4; ++kc) {                                         \
        bf16x8 kf = *(const bf16x8*)&(KL)[(nb * 16 + lr) * KSTR + kc * 32 + g * 8]; \
        a0 = __builtin_amdgcn_mfma_f32_16x16x32_bf16(kf, qf[0][kc], a0, 0, 0, 0);   \
        a1 = __builtin_amdgcn_mfma_f32_16x16x32_bf16(kf, qf[1][kc], a1, 0, 0, 0);   \
      }                                                                        \
      sacc[0][nb] = a0;                                                        \
      sacc[1][nb] = a1;                                                        \
    }                                                                          \
    __builtin_amdgcn_s_setprio(0);                                             \
    _Pragma("unroll")                                                          \
    for (int qt = 0; qt < 2; ++qt) {                                           \
      _Pragma("unroll")                                                        \
      for (int nb = 0; nb < 4; ++nb)                                           \
        _Pragma("unroll")                                                      \
        for (int i = 0; i < 4; ++i) {                                          \
          float p = exp2f(sacc[qt][nb][i]);                                    \
          sacc[qt][nb][i] = p;                                                 \
          lpart[qt] += p;                                                      \
        }                                                                      \
      bf16x8 t0, t1;                                                           \
      _Pragma("unroll")                                                        \
      for (int i = 0; i < 4; ++i) {                                            \
        t0[i]     = (__bf16)sacc[qt][0][i];                                    \
        t0[i + 4] = (__bf16)sacc[qt][1][i];                                    \
        t1[i]     = (__bf16)sacc[qt][2][i];                                    \
        t1[i + 4] = (__bf16)sacc[qt][3][i];                                    \
      }                                                                        \
      pf[qt][0] = t0;                                                          \
      pf[qt][1] = t1;                                                          \
    }                                                                          \
  }

#define PV_STEP(VL)                                                            \
  {                                                                            \
    __builtin_amdgcn_s_setprio(1);                                             \
    _Pragma("unroll")                                                          \
    for (int dc = 0; dc < 8; ++dc) {                                           \
      bf16x8 vf0 = *(const bf16x8*)&(VL)[(dc * 16 + lr) * VSTR + g * 8];       \
      bf16x8 vf1 = *(const bf16x8*)&(VL)[(dc * 16 + lr) * VSTR + 32 + g * 8];  \
      oacc[0][dc] = __builtin_amdgcn_mfma_f32_16x16x32_bf16(pf[0][0], vf0, oacc[0][dc], 0, 0, 0); \
      oacc[1][dc] = __builtin_amdgcn_mfma_f32_16x16x32_bf16(pf[1][0], vf0, oacc[1][dc], 0, 0, 0); \
      oacc[0][dc] = __builtin_amdgcn_mfma_f32_16x16x32_bf16(pf[0][1], vf1, oacc[0][dc], 0, 0, 0); \
      oacc[1][dc] = __builtin_amdgcn_mfma_f32_16x16x32_bf16(pf[1][1], vf1, oacc[1][dc], 0, 0, 0); \
    }                                                                          \
    __builtin_amdgcn_s_setprio(0);                                             \
  }

  // ---- prologue: tile 0 (no PV yet) ----
  LOAD_NEXT;                       // tile 0 -> regs
  WRITE_LDS(kbuf[0], vbuf[0]);
  LOAD_NEXT;                       // tile 1 -> regs (in flight across barrier)
  __syncthreads();
  QK_SOFTMAX(kbuf[0]);

  // ---- main loop: tiles 1..NT-1 ----
#pragma unroll 2
  for (int kt = 1; kt < NT; ++kt) {
    short* kl  = kbuf[kt & 1];
    short* vl  = vbuf[kt & 1];
    short* vlp = vbuf[(kt & 1) ^ 1];

    WRITE_LDS(kl, vl);             // staged regs (tile kt) -> LDS
    if (kt + 1 < NT) LOAD_NEXT;    // issue tile kt+1 loads
    PV_STEP(vlp);                  // deferred PV(kt-1)
    __syncthreads();               // single barrier: K/V(kt) visible, PV(kt-1) drained
    QK_SOFTMAX(kl);                // S^T = K Q^T, exp, pack -> pf
  }

  // ---- epilogue: PV(NT-1) ----
  {
    short* vlp = vbuf[(NT - 1) & 1];
    PV_STEP(vlp);
  }

  // ---- final row-sum reduce, normalize, store ----
#pragma unroll
  for (int qt = 0; qt < 2; ++qt) {
    float l = lpart[qt];
    l += __shfl_xor(l, 16);
    l += __shfl_xor(l, 32);
    float inv = 1.0f / l;
#pragma unroll
    for (int i = 0; i < 4; ++i) {
      float invm = __shfl(inv, g * 4 + i);
      float* orow = Ob + (size_t)(wq0 + qt * 16 + g * 4 + i) * SROW;
#pragma unroll
      for (int dc = 0; dc < 8; ++dc)
        orow[dc * 16 + lr] = oacc[qt][dc][i] * invm;
    }
  }
#undef LOAD_NEXT
#undef WRITE_LDS
#undef QK_SOFTMAX
#undef PV_STEP
}

// ---------------- legacy fallback (fp32 staging, QBLK=64) ----------------
__global__ __launch_bounds__(256, 2)
void attn_fwd_legacy(const float* __restrict__ Q, const float* __restrict__ K,
                     const float* __restrict__ V, float* __restrict__ O)
{
  __shared__ __align__(16) short k_lds[KBLK * KSTR];
  __shared__ __align__(16) short vt_lds[ND * VSTR];
  __shared__ __align__(16) short p_lds[4 * 16 * 72];

  const int tid = threadIdx.x;
  const int wave = tid >> 6;
  const int lane = tid & 63;
  const int g = lane >> 4;
  const int lr = lane & 15;

  const int nqb = NS / 64;
  const int qb = blockIdx.x % nqb;
  const int bh = blockIdx.x / nqb;
  const int b = bh / NH;
  const int h = bh % NH;

  const float scale = 0.08838834764831845f * 1.4426950408889634f;
  const size_t base = ((size_t)b * NS * NH + h) * ND;
  const float* Qb = Q + base;
  const float* Kbp = K + base;
  const float* Vb = V + base;
  float* Ob = O + base;
  const int q0 = qb * 64 + wave * 16;

  bf16x8 qf[4];
  {
    const float* qp = Qb + (size_t)(q0 + lr) * SROW;
#pragma unroll
    for (int kc = 0; kc < 4; ++kc) {
      const int d0 = kc * 32 + g * 8;
      float4 a = *(const float4*)(qp + d0);
      float4 c = *(const float4*)(qp + d0 + 4);
      s16x8 f;
      f[0] = f2bf(a.x * scale); f[1] = f2bf(a.y * scale);
      f[2] = f2bf(a.z * scale); f[3] = f2bf(a.w * scale);
      f[4] = f2bf(c.x * scale); f[5] = f2bf(c.y * scale);
      f[6] = f2bf(c.z * scale); f[7] = f2bf(c.w * scale);
      qf[kc] = __builtin_bit_cast(bf16x8, f);
    }
  }

  f32x4 oacc[8];
#pragma unroll
  for (int dc = 0; dc < 8; ++dc) oacc[dc] = (f32x4){0.f, 0.f, 0.f, 0.f};
  float mrun[4] = {-1e30f, -1e30f, -1e30f, -1e30f};
  float lrun[4] = {0.f, 0.f, 0.f, 0.f};

  for (int kt = 0; kt < NS / KBLK; ++kt) {
    const int kv0 = kt * KBLK;
    __syncthreads();
#pragma unroll
    for (int it = 0; it < 8; ++it) {
      int idx = tid + it * 256;
      int r = idx >> 5;
      int c = (idx & 31) << 2;
      float4 x = *(const float4*)(Kbp + (size_t)(kv0 + r) * SROW + c);
      s16x4 w = { f2bf(x.x), f2bf(x.y), f2bf(x.z), f2bf(x.w) };
      *(s16x4*)&k_lds[r * KSTR + c] = w;
    }
#pragma unroll
    for (int it = 0; it < 2; ++it) {
      int sub = tid + it * 256;
      int skv = (sub >> 5) << 2;
      int sd = (sub & 31) << 2;
      const float* vp = Vb + (size_t)(kv0 + skv) * SROW + sd;
      float4 r0 = *(const float4*)(vp);
      float4 r1 = *(const float4*)(vp + SROW);
      float4 r2 = *(const float4*)(vp + 2 * SROW);
      float4 r3 = *(const float4*)(vp + 3 * SROW);
      s16x4 w0 = { f2bf(r0.x), f2bf(r1.x), f2bf(r2.x), f2bf(r3.x) };
      s16x4 w1 = { f2bf(r0.y), f2bf(r1.y), f2bf(r2.y), f2bf(r3.y) };
      s16x4 w2 = { f2bf(r0.z), f2bf(r1.z), f2bf(r2.z), f2bf(r3.z) };
      s16x4 w3 = { f2bf(r0.w), f2bf(r1.w), f2bf(r2.w), f2bf(r3.w) };
      *(s16x4*)&vt_lds[(sd + 0) * VSTR + skv] = w0;
      *(s16x4*)&vt_lds[(sd + 1) * VSTR + skv] = w1;
      *(s16x4*)&vt_lds[(sd + 2) * VSTR + skv] = w2;
      *(s16x4*)&vt_lds[(sd + 3) * VSTR + skv] = w3;
    }
    __syncthreads();

    f32x4 sacc[4];
#pragma unroll
    for (int nb = 0; nb < 4; ++nb) {
      f32x4 acc = {0.f, 0.f, 0.f, 0.f};
#pragma unroll
      for (int kc = 0; kc < 4; ++kc) {
        bf16x8 kf = *(const bf16x8*)&k_lds[(nb * 16 + lr) * KSTR + kc * 32 + g * 8];
        acc = __builtin_amdgcn_mfma_f32_16x16x32_bf16(qf[kc], kf, acc, 0, 0, 0);
      }
      sacc[nb] = acc;
    }

    float alpha[4];
#pragma unroll
    for (int i = 0; i < 4; ++i) {
      float m = fmaxf(fmaxf(sacc[0][i], sacc[1][i]), fmaxf(sacc[2][i], sacc[3][i]));
#pragma unroll
      for (int off = 1; off < 16; off <<= 1) m = fmaxf(m, __shfl_xor(m, off));
      float mnew = fmaxf(mrun[i], m);
      alpha[i] = exp2f(mrun[i] - mnew);
      mrun[i] = mnew;
    }
    float rsum[4] = {0.f, 0.f, 0.f, 0.f};
#pragma unroll
    for (int nb = 0; nb < 4; ++nb)
#pragma unroll
      for (int i = 0; i < 4; ++i) {
        float p = exp2f(sacc[nb][i] - mrun[i]);
        sacc[nb][i] = p;
        rsum[i] += p;
      }
#pragma unroll
    for (int i = 0; i < 4; ++i) {
#pragma unroll
      for (int off = 1; off < 16; off <<= 1) rsum[i] += __shfl_xor(rsum[i], off);
      lrun[i] = lrun[i] * alpha[i] + rsum[i];
    }
#pragma unroll
    for (int dc = 0; dc < 8; ++dc)
#pragma unroll
      for (int i = 0; i < 4; ++i) oacc[dc][i] *= alpha[i];

    short* pw = &p_lds[wave * 16 * 72];
#pragma unroll
    for (int nb = 0; nb < 4; ++nb)
#pragma unroll
      for (int i = 0; i < 4; ++i)
        pw[(g * 4 + i) * 72 + nb * 16 + lr] = f2bf(sacc[nb][i]);

    bf16x8 pf0 = *(const bf16x8*)&pw[lr * 72 + g * 8];
    bf16x8 pf1 = *(const bf16x8*)&pw[lr * 72 + 32 + g * 8];

#pragma unroll
    for (int dc = 0; dc < 8; ++dc) {
      bf16x8 vf0 = *(const bf16x8*)&vt_lds[(dc * 16 + lr) * VSTR + g * 8];
      oacc[dc] = __builtin_amdgcn_mfma_f32_16x16x32_bf16(pf0, vf0, oacc[dc], 0, 0, 0);
      bf16x8 vf1 = *(const bf16x8*)&vt_lds[(dc * 16 + lr) * VSTR + 32 + g * 8];
      oacc[dc] = __builtin_amdgcn_mfma_f32_16x16x32_bf16(pf1, vf1, oacc[dc], 0, 0, 0);
    }
  }

  float* op = Ob + (size_t)q0 * SROW;
#pragma unroll
  for (int i = 0; i < 4; ++i) {
    float inv = 1.0f / lrun[i];
    int m = g * 4 + i;
#pragma unroll
    for (int dc = 0; dc < 8; ++dc)
      op[(size_t)m * SROW + dc * 16 + lr] = oacc[dc][i] * inv;
  }
}

extern "C" void kernel_launch(void* const* d_in, const int* in_sizes, int n_in,
                              void* d_out, int out_size, void* d_ws, size_t ws_size,
                              hipStream_t stream) {
  const float* Q = (const float*)d_in[0];
  const float* K = (const float*)d_in[1];
  const float* V = (const float*)d_in[2];
  float* O = (float*)d_out;

  const size_t elems = (size_t)NB * NS * NH * ND;      // 8388608
  const size_t need = 2 * elems * sizeof(short);       // 33.5 MB

  if (ws_size >= need) {
    short* Kb = (short*)d_ws;
    short* VT = Kb + elems;
    hipLaunchKernelGGL(prep_k, dim3((unsigned)(elems / 4 / 256)), dim3(256), 0, stream, K, Kb);
    hipLaunchKernelGGL(prep_v, dim3(NB * NH * (NS / 64) * (ND / 64)), dim3(256), 0, stream, V, VT);
    hipLaunchKernelGGL(attn_fwd7, dim3(NB * NH * (NS / QBLK)), dim3(NTHR), 0, stream, Q, Kb, VT, O);
  } else {
    hipLaunchKernelGGL(attn_fwd_legacy, dim3(NB * NH * (NS / 64)), dim3(256), 0, stream, Q, K, V, O);
  }
}